// Round 3
// baseline (753.204 us; speedup 1.0000x reference)
//
#include <hip/hip_runtime.h>
#include <hip/hip_bf16.h>
#include <stdint.h>

typedef float f32x4 __attribute__((ext_vector_type(4)));
typedef __bf16 bf16x8 __attribute__((ext_vector_type(8)));
typedef unsigned short u16x4 __attribute__((ext_vector_type(4)));
typedef unsigned short u16x8 __attribute__((ext_vector_type(8)));

#define DEV __device__ __forceinline__
#define NEG_BIG (-3.0e38f)

DEV f32x4 mfma16(bf16x8 a, bf16x8 b, f32x4 c) {
  return __builtin_amdgcn_mfma_f32_16x16x32_bf16(a, b, c, 0, 0, 0);
}

// global -> LDS direct copy, 16B per lane. LDS dest is wave-uniform base;
// HW writes base + lane*16. Global src is per-lane.
DEV void gl_lds16(const void* g, void* l) {
  __builtin_amdgcn_global_load_lds(
      (const __attribute__((address_space(1))) void*)g,
      (__attribute__((address_space(3))) void*)l,
      16, 0, 0);
}

DEV void wait_vm0() {
  asm volatile("s_waitcnt vmcnt(0)" ::: "memory");
  __builtin_amdgcn_sched_barrier(0);
}

DEV unsigned short f2bfu(float f) {
  __hip_bfloat16 h = __float2bfloat16(f);
  return __builtin_bit_cast(unsigned short, h);
}

// ---------------------------------------------------------------------------
// f32 -> bf16 conversion (vectorized: float4 in, 4x bf16 out). n % 4 == 0.
// ---------------------------------------------------------------------------
__global__ __launch_bounds__(256) void cvt_f32_bf16(
    const float* __restrict__ src, __hip_bfloat16* __restrict__ dst, int n4)
{
  const int i = blockIdx.x * 256 + threadIdx.x;
  if (i >= n4) return;
  const float4 v = ((const float4*)src)[i];
  u16x4 o;
  o[0] = f2bfu(v.x); o[1] = f2bfu(v.y); o[2] = f2bfu(v.z); o[3] = f2bfu(v.w);
  ((u16x4*)dst)[i] = o;
}

// ---------------------------------------------------------------------------
// GEMM: C[m,n] = sum_k A[m,k] * B[n,k]   (A: MxK bf16 row-major, B: NxK bf16)
// 128x128 tile, BK=32, 4 waves (2x2 of 64x64), double-buffered LDS,
// 2-phase schedule: stage(next) -> compute(cur) -> barrier.
// OutT: __hip_bfloat16 or float.
// ---------------------------------------------------------------------------
DEV void storeC(__hip_bfloat16* C, size_t idx, float v) { C[idx] = __float2bfloat16(v); }
DEV void storeC(float* C, size_t idx, float v) { C[idx] = v; }

template <typename OutT>
__global__ __launch_bounds__(256) void gemm_bt(
    const __hip_bfloat16* __restrict__ A,
    const __hip_bfloat16* __restrict__ B,
    OutT* __restrict__ C,
    int M, int N, int K, int ldc)
{
  __shared__ __align__(16) unsigned short ldsA[2][128 * 32];
  __shared__ __align__(16) unsigned short ldsB[2][128 * 32];

  const int tid  = threadIdx.x;
  const int w    = tid >> 6;
  const int lane = tid & 63;
  const int mbase = blockIdx.y * 128;
  const int nbase = blockIdx.x * 128;
  const int wr = (w >> 1) * 64;
  const int wc = (w & 1) * 64;

  // staging: thread t covers row t>>2 (+64 for i=1), k cols (t&3)*8..+7
  const int srow = tid >> 2;
  const int scol = (tid & 3) * 8;
  const __hip_bfloat16* Ag = A + (size_t)(mbase + srow) * K + scol;
  const __hip_bfloat16* Bg = B + (size_t)(nbase + srow) * K + scol;

  f32x4 acc[4][4] = {};

  const int KT = K >> 5;
  int cur = 0;

  #pragma unroll
  for (int i = 0; i < 2; ++i) {
    gl_lds16(Ag + (size_t)i * 64 * K, &ldsA[0][i * 2048 + w * 512]);
    gl_lds16(Bg + (size_t)i * 64 * K, &ldsB[0][i * 2048 + w * 512]);
  }
  wait_vm0();
  __syncthreads();

  const int arow = wr + (lane & 15);
  const int brow = wc + (lane & 15);
  const int koff = (lane >> 4) * 8;

  for (int kt = 0; kt < KT; ++kt) {
    if (kt + 1 < KT) {
      const int k0 = (kt + 1) << 5;
      #pragma unroll
      for (int i = 0; i < 2; ++i) {
        gl_lds16(Ag + (size_t)i * 64 * K + k0, &ldsA[cur ^ 1][i * 2048 + w * 512]);
        gl_lds16(Bg + (size_t)i * 64 * K + k0, &ldsB[cur ^ 1][i * 2048 + w * 512]);
      }
    }
    bf16x8 af[4], bfr[4];
    #pragma unroll
    for (int mi = 0; mi < 4; ++mi)
      af[mi] = *(const bf16x8*)&ldsA[cur][(arow + mi * 16) * 32 + koff];
    #pragma unroll
    for (int ni = 0; ni < 4; ++ni)
      bfr[ni] = *(const bf16x8*)&ldsB[cur][(brow + ni * 16) * 32 + koff];
    #pragma unroll
    for (int mi = 0; mi < 4; ++mi)
      #pragma unroll
      for (int ni = 0; ni < 4; ++ni)
        acc[mi][ni] = mfma16(af[mi], bfr[ni], acc[mi][ni]);
    wait_vm0();        // staged loads landed before barrier release
    __syncthreads();
    cur ^= 1;
  }

  #pragma unroll
  for (int mi = 0; mi < 4; ++mi)
    #pragma unroll
    for (int ni = 0; ni < 4; ++ni)
      #pragma unroll
      for (int j = 0; j < 4; ++j) {
        const int m = mbase + wr + mi * 16 + (lane >> 4) * 4 + j;
        const int n = nbase + wc + ni * 16 + (lane & 15);
        storeC(C, (size_t)m * ldc + n, acc[mi][ni][j]);
      }
}

// ---------------------------------------------------------------------------
// Per-head RMSNorm + RoPE, in-place on the fused bf16 qkv buffer.
// One wave per 128-d head vector; lane handles elems l and l+64.
// rope/qw/kw are f32 (reference dtype).
// ---------------------------------------------------------------------------
__global__ __launch_bounds__(256) void rmsnorm_rope(
    __hip_bfloat16* __restrict__ qkv,
    const float* __restrict__ rope,
    const float* __restrict__ qw,
    const float* __restrict__ kw)
{
  const int v = blockIdx.x * 4 + (threadIdx.x >> 6);
  const int lane = threadIdx.x & 63;
  const int row = v / 20;          // b*2048+s
  const int hh  = v % 20;          // 0..15 q heads, 16..19 k heads
  const int s   = row & 2047;

  __hip_bfloat16* p = qkv + (size_t)row * 3072 +
                      (hh < 16 ? hh * 128 : 2048 + (hh - 16) * 128);
  const float* wn = (hh < 16) ? qw : kw;

  float x0 = __bfloat162float(p[lane]);
  float x1 = __bfloat162float(p[lane + 64]);
  float ss = x0 * x0 + x1 * x1;
  #pragma unroll
  for (int off = 1; off < 64; off <<= 1) ss += __shfl_xor(ss, off);
  const float rn = rsqrtf(ss * (1.0f / 128.0f) + 1e-6f);
  x0 *= rn * wn[lane];
  x1 *= rn * wn[lane + 64];

  const float* rc = rope + (size_t)s * 256;
  const float c0 = rc[lane];
  const float c1 = rc[64 + lane];
  const float s0 = rc[128 + lane];
  const float s1 = rc[192 + lane];

  p[lane]      = __float2bfloat16(x0 * c0 - x1 * s0);
  p[lane + 64] = __float2bfloat16(x1 * c1 + x0 * s1);
}

// ---------------------------------------------------------------------------
// Causal GQA flash attention. Block = (qt, h, b): 64 q rows, 4 waves x 16 rows.
// KV tiles of 32. QK^T and PV via mfma_f32_16x16x32_bf16.
// ---------------------------------------------------------------------------
__global__ __launch_bounds__(256) void attn_fwd(
    const __hip_bfloat16* __restrict__ qkv,
    __hip_bfloat16* __restrict__ O)
{
  __shared__ __align__(16) unsigned short ldsK[32 * 128];   // [kv][d]
  __shared__ __align__(16) unsigned short ldsVT[128 * 32];  // [d][kv]
  __shared__ __align__(16) unsigned short ldsP[4][16 * 32]; // per-wave P tile

  const int tid  = threadIdx.x;
  const int w    = tid >> 6;
  const int lane = tid & 63;
  const int qt = blockIdx.x;   // 0..31
  const int h  = blockIdx.y;   // 0..15
  const int b  = blockIdx.z;   // 0..1
  const int hkv = h >> 2;

  const size_t LDQ = 3072;
  const __hip_bfloat16* Qb = qkv + (size_t)b * 2048 * LDQ + h * 128;
  const __hip_bfloat16* Kb = qkv + (size_t)b * 2048 * LDQ + 2048 + hkv * 128;
  const __hip_bfloat16* Vb = qkv + (size_t)b * 2048 * LDQ + 2560 + hkv * 128;

  const int koff = (lane >> 4) * 8;
  const int qrow = qt * 64 + w * 16 + (lane & 15);

  bf16x8 qf[4];
  #pragma unroll
  for (int dt = 0; dt < 4; ++dt)
    qf[dt] = *(const bf16x8*)(Qb + (size_t)qrow * LDQ + dt * 32 + koff);

  f32x4 po[8] = {};
  float mrow[4] = {NEG_BIG, NEG_BIG, NEG_BIG, NEG_BIG};
  float lrow[4] = {0.f, 0.f, 0.f, 0.f};

  const int nt = 2 * qt + 2;
  const int qmaxw = qt * 64 + w * 16 + 15;
  const int q0 = qt * 64 + w * 16 + (lane >> 4) * 4;

  const int sr  = tid >> 4;        // staging row 0..15 (+16 for i=1)
  const int sc8 = (tid & 15) * 8;  // staging col (elements)

  for (int t = 0; t < nt; ++t) {
    const int kv0 = t * 32;
    // K tile -> LDS row-major [32][128] via global_load_lds (lane-contiguous)
    #pragma unroll
    for (int i = 0; i < 2; ++i)
      gl_lds16(Kb + (size_t)(kv0 + sr + i * 16) * LDQ + sc8,
               &ldsK[i * 2048 + w * 512]);
    // V tile -> LDS transposed [128][32]
    #pragma unroll
    for (int i = 0; i < 2; ++i) {
      const int r = sr + i * 16;
      u16x8 vv = *(const u16x8*)(Vb + (size_t)(kv0 + r) * LDQ + sc8);
      #pragma unroll
      for (int j = 0; j < 8; ++j)
        ldsVT[(sc8 + j) * 32 + r] = vv[j];
    }
    wait_vm0();
    __syncthreads();

    if (kv0 <= qmaxw) {
      // ---- QK^T: S[q, kv] for 16q x 32kv ----
      f32x4 st[2];
      #pragma unroll
      for (int sub = 0; sub < 2; ++sub) {
        f32x4 s = {};
        const int kvloc = sub * 16 + (lane & 15);
        #pragma unroll
        for (int dt = 0; dt < 4; ++dt) {
          bf16x8 kf = *(const bf16x8*)&ldsK[kvloc * 128 + dt * 32 + koff];
          s = mfma16(qf[dt], kf, s);
        }
        st[sub] = s;
      }
      // ---- scale + causal mask ----
      #pragma unroll
      for (int sub = 0; sub < 2; ++sub)
        #pragma unroll
        for (int j = 0; j < 4; ++j) {
          const float val = st[sub][j] * 0.08838834764831845f;
          const int kv = kv0 + sub * 16 + (lane & 15);
          st[sub][j] = (kv > q0 + j) ? NEG_BIG : val;
        }
      // ---- online softmax: row reductions across 16 lanes ----
      float pm[4];
      #pragma unroll
      for (int j = 0; j < 4; ++j) pm[j] = fmaxf(st[0][j], st[1][j]);
      #pragma unroll
      for (int off = 1; off < 16; off <<= 1)
        #pragma unroll
        for (int j = 0; j < 4; ++j) pm[j] = fmaxf(pm[j], __shfl_xor(pm[j], off));
      float corr[4];
      #pragma unroll
      for (int j = 0; j < 4; ++j) {
        const float mn = fmaxf(mrow[j], pm[j]);
        corr[j] = __expf(mrow[j] - mn);   // finite sentinel: underflows to 0
        mrow[j] = mn;
      }
      float rs[4] = {0.f, 0.f, 0.f, 0.f};
      #pragma unroll
      for (int sub = 0; sub < 2; ++sub)
        #pragma unroll
        for (int j = 0; j < 4; ++j) {
          const float pv = __expf(st[sub][j] - mrow[j]);
          st[sub][j] = pv;
          rs[j] += pv;
        }
      #pragma unroll
      for (int off = 1; off < 16; off <<= 1)
        #pragma unroll
        for (int j = 0; j < 4; ++j) rs[j] += __shfl_xor(rs[j], off);
      #pragma unroll
      for (int j = 0; j < 4; ++j) lrow[j] = lrow[j] * corr[j] + rs[j];
      #pragma unroll
      for (int dt = 0; dt < 8; ++dt)
        #pragma unroll
        for (int j = 0; j < 4; ++j) po[dt][j] *= corr[j];

      // ---- P (D-layout) -> LDS -> A-operand layout (same wave only) ----
      #pragma unroll
      for (int sub = 0; sub < 2; ++sub)
        #pragma unroll
        for (int j = 0; j < 4; ++j)
          ldsP[w][((lane >> 4) * 4 + j) * 32 + sub * 16 + (lane & 15)] =
              f2bfu(st[sub][j]);
      asm volatile("s_waitcnt lgkmcnt(0)" ::: "memory");
      __builtin_amdgcn_sched_barrier(0);
      bf16x8 pf = *(const bf16x8*)&ldsP[w][(lane & 15) * 32 + koff];

      // ---- PV: O[q, d] += P(16x32) * V(32x16 per dt) ----
      #pragma unroll
      for (int dt = 0; dt < 8; ++dt) {
        bf16x8 vf = *(const bf16x8*)&ldsVT[(dt * 16 + (lane & 15)) * 32 + koff];
        po[dt] = mfma16(pf, vf, po[dt]);
      }
    }
    __syncthreads();
  }

  #pragma unroll
  for (int j = 0; j < 4; ++j) {
    const float inv = 1.0f / lrow[j];
    const int q = q0 + j;
    #pragma unroll
    for (int dt = 0; dt < 8; ++dt)
      O[((size_t)b * 2048 + q) * 2048 + h * 128 + dt * 16 + (lane & 15)] =
          __float2bfloat16(po[dt][j] * inv);
  }
}

// ---------------------------------------------------------------------------
extern "C" void kernel_launch(void* const* d_in, const int* in_sizes, int n_in,
                              void* d_out, int out_size, void* d_ws, size_t ws_size,
                              hipStream_t stream) {
  (void)in_sizes; (void)n_in; (void)out_size; (void)ws_size;
  // Reference dtypes: ALL inputs are float32; output is float32.
  const float* x    = (const float*)d_in[0];
  const float* rope = (const float*)d_in[1];
  const float* wq   = (const float*)d_in[2];
  const float* wk   = (const float*)d_in[3];
  const float* wv   = (const float*)d_in[4];
  const float* wo   = (const float*)d_in[5];
  const float* qnw  = (const float*)d_in[6];
  const float* knw  = (const float*)d_in[7];
  float* out = (float*)d_out;

  // Workspace (bf16): xb | wqkv_b | wo_b | qkv | att  = 79.7 MB total
  __hip_bfloat16* xb  = (__hip_bfloat16*)d_ws;            // 4096 x 2048
  __hip_bfloat16* wb  = xb  + (size_t)4096 * 2048;        // 3072 x 2048 (wq|wk|wv)
  __hip_bfloat16* wob = wb  + (size_t)3072 * 2048;        // 2048 x 2048
  __hip_bfloat16* qkv = wob + (size_t)2048 * 2048;        // 4096 x 3072
  __hip_bfloat16* att = qkv + (size_t)4096 * 3072;        // 4096 x 2048

  // f32 -> bf16 conversions
  cvt_f32_bf16<<<8192, 256, 0, stream>>>(x,  xb,  2097152);
  cvt_f32_bf16<<<4096, 256, 0, stream>>>(wq, wb,                     1048576);
  cvt_f32_bf16<<<1024, 256, 0, stream>>>(wk, wb + (size_t)2048*2048,  262144);
  cvt_f32_bf16<<<1024, 256, 0, stream>>>(wv, wb + (size_t)2560*2048,  262144);
  cvt_f32_bf16<<<4096, 256, 0, stream>>>(wo, wob,                    1048576);

  // Fused QKV projection: [4096,2048] x [3072,2048]^T -> qkv [4096,3072]
  gemm_bt<__hip_bfloat16><<<dim3(24, 32), 256, 0, stream>>>(
      xb, wb, qkv, 4096, 3072, 2048, 3072);
  // per-head RMSNorm + RoPE on q,k (in place)
  rmsnorm_rope<<<20480, 256, 0, stream>>>(qkv, rope, qnw, knw);
  // causal GQA attention
  attn_fwd<<<dim3(32, 16, 2), 256, 0, stream>>>(qkv, att);
  // output projection -> f32 out
  gemm_bt<float><<<dim3(16, 32), 256, 0, stream>>>(
      att, wob, out, 4096, 2048, 2048, 2048);
}

// Round 5
// 421.970 us; speedup vs baseline: 1.7850x; 1.7850x over previous
//
#include <hip/hip_runtime.h>
#include <hip/hip_bf16.h>
#include <stdint.h>

typedef float f32x4 __attribute__((ext_vector_type(4)));
typedef __bf16 bf16x8 __attribute__((ext_vector_type(8)));
typedef unsigned short u16x4 __attribute__((ext_vector_type(4)));

#define DEV __device__ __forceinline__
#define NEG_BIG (-3.0e38f)

DEV f32x4 mfma16(bf16x8 a, bf16x8 b, f32x4 c) {
  return __builtin_amdgcn_mfma_f32_16x16x32_bf16(a, b, c, 0, 0, 0);
}

// global -> LDS direct copy, 16B per lane. LDS dest is wave-uniform base;
// HW writes base + lane*16. Global src is per-lane.
DEV void gl_lds16(const void* g, void* l) {
  __builtin_amdgcn_global_load_lds(
      (const __attribute__((address_space(1))) void*)g,
      (__attribute__((address_space(3))) void*)l,
      16, 0, 0);
}

DEV void wait_vm0() {
  asm volatile("s_waitcnt vmcnt(0)" ::: "memory");
  __builtin_amdgcn_sched_barrier(0);
}

DEV unsigned short f2bfu(float f) {
  __hip_bfloat16 h = __float2bfloat16(f);
  return __builtin_bit_cast(unsigned short, h);
}

// ---------------------------------------------------------------------------
// f32 -> bf16 conversion (vectorized). n4 = n/4.
// ---------------------------------------------------------------------------
__global__ __launch_bounds__(256) void cvt_f32_bf16(
    const float* __restrict__ src, __hip_bfloat16* __restrict__ dst, int n4)
{
  const int i = blockIdx.x * 256 + threadIdx.x;
  if (i >= n4) return;
  const float4 v = ((const float4*)src)[i];
  u16x4 o;
  o[0] = f2bfu(v.x); o[1] = f2bfu(v.y); o[2] = f2bfu(v.z); o[3] = f2bfu(v.w);
  ((u16x4*)dst)[i] = o;
}

// ---------------------------------------------------------------------------
// GEMM: C = A * B^T  (A: MxK bf16, B: NxK bf16). 128x128 tile, BK=32, dbuf.
// TRANS=true writes C transposed: C[n*ldc + m] (used to emit V^T directly).
// ---------------------------------------------------------------------------
DEV void storeC(__hip_bfloat16* C, size_t idx, float v) { C[idx] = __float2bfloat16(v); }
DEV void storeC(float* C, size_t idx, float v) { C[idx] = v; }

template <typename OutT, bool TRANS>
__global__ __launch_bounds__(256) void gemm_bt(
    const __hip_bfloat16* __restrict__ A,
    const __hip_bfloat16* __restrict__ B,
    OutT* __restrict__ C,
    int M, int N, int K, int ldc)
{
  __shared__ __align__(16) unsigned short ldsA[2][128 * 32];
  __shared__ __align__(16) unsigned short ldsB[2][128 * 32];

  const int tid  = threadIdx.x;
  const int w    = tid >> 6;
  const int lane = tid & 63;
  const int mbase = blockIdx.y * 128;
  const int nbase = blockIdx.x * 128;
  const int wr = (w >> 1) * 64;
  const int wc = (w & 1) * 64;

  const int srow = tid >> 2;
  const int scol = (tid & 3) * 8;
  const __hip_bfloat16* Ag = A + (size_t)(mbase + srow) * K + scol;
  const __hip_bfloat16* Bg = B + (size_t)(nbase + srow) * K + scol;

  f32x4 acc[4][4] = {};

  const int KT = K >> 5;
  int cur = 0;

  #pragma unroll
  for (int i = 0; i < 2; ++i) {
    gl_lds16(Ag + (size_t)i * 64 * K, &ldsA[0][i * 2048 + w * 512]);
    gl_lds16(Bg + (size_t)i * 64 * K, &ldsB[0][i * 2048 + w * 512]);
  }
  wait_vm0();
  __syncthreads();

  const int arow = wr + (lane & 15);
  const int brow = wc + (lane & 15);
  const int koff = (lane >> 4) * 8;

  for (int kt = 0; kt < KT; ++kt) {
    if (kt + 1 < KT) {
      const int k0 = (kt + 1) << 5;
      #pragma unroll
      for (int i = 0; i < 2; ++i) {
        gl_lds16(Ag + (size_t)i * 64 * K + k0, &ldsA[cur ^ 1][i * 2048 + w * 512]);
        gl_lds16(Bg + (size_t)i * 64 * K + k0, &ldsB[cur ^ 1][i * 2048 + w * 512]);
      }
    }
    bf16x8 af[4], bfr[4];
    #pragma unroll
    for (int mi = 0; mi < 4; ++mi)
      af[mi] = *(const bf16x8*)&ldsA[cur][(arow + mi * 16) * 32 + koff];
    #pragma unroll
    for (int ni = 0; ni < 4; ++ni)
      bfr[ni] = *(const bf16x8*)&ldsB[cur][(brow + ni * 16) * 32 + koff];
    #pragma unroll
    for (int mi = 0; mi < 4; ++mi)
      #pragma unroll
      for (int ni = 0; ni < 4; ++ni)
        acc[mi][ni] = mfma16(af[mi], bfr[ni], acc[mi][ni]);
    wait_vm0();
    __syncthreads();
    cur ^= 1;
  }

  #pragma unroll
  for (int mi = 0; mi < 4; ++mi)
    #pragma unroll
    for (int ni = 0; ni < 4; ++ni)
      #pragma unroll
      for (int j = 0; j < 4; ++j) {
        const int m = mbase + wr + mi * 16 + (lane >> 4) * 4 + j;
        const int n = nbase + wc + ni * 16 + (lane & 15);
        if (TRANS) storeC(C, (size_t)n * ldc + m, acc[mi][ni][j]);
        else       storeC(C, (size_t)m * ldc + n, acc[mi][ni][j]);
      }
}

// ---------------------------------------------------------------------------
// Per-head RMSNorm + RoPE, in-place on the bf16 qk buffer (stride 2560).
// ---------------------------------------------------------------------------
__global__ __launch_bounds__(256) void rmsnorm_rope(
    __hip_bfloat16* __restrict__ qk,
    const float* __restrict__ rope,
    const float* __restrict__ qw,
    const float* __restrict__ kw)
{
  const int v = blockIdx.x * 4 + (threadIdx.x >> 6);
  const int lane = threadIdx.x & 63;
  const int row = v / 20;
  const int hh  = v % 20;
  const int s   = row & 2047;

  __hip_bfloat16* p = qk + (size_t)row * 2560 +
                      (hh < 16 ? hh * 128 : 2048 + (hh - 16) * 128);
  const float* wn = (hh < 16) ? qw : kw;

  float x0 = __bfloat162float(p[lane]);
  float x1 = __bfloat162float(p[lane + 64]);
  float ss = x0 * x0 + x1 * x1;
  #pragma unroll
  for (int off = 1; off < 64; off <<= 1) ss += __shfl_xor(ss, off);
  const float rn = rsqrtf(ss * (1.0f / 128.0f) + 1e-6f);
  x0 *= rn * wn[lane];
  x1 *= rn * wn[lane + 64];

  const float* rc = rope + (size_t)s * 256;
  p[lane]      = __float2bfloat16(x0 * rc[lane]      - x1 * rc[128 + lane]);
  p[lane + 64] = __float2bfloat16(x1 * rc[64 + lane] + x0 * rc[192 + lane]);
}

// ---------------------------------------------------------------------------
// Causal GQA flash attention.
//  - block (qtA, h, b) handles q-tiles qtA and 31-qtA: uniform 66 KV tiles
//  - K: [32 kv][128 d] LDS, both-sides XOR swizzle (slot ^= kv&7)
//  - V: staged from global V^T [hd=512][bs=4096]; LDS [128 d][32 kv],
//       kv-slot swizzle (slot ^= (d>>2)&3) applied at source and read
//  - P: per-wave [16][40] (padded stride)
//  - double-buffered K/V: stage(t+1) issued before compute(t)
// ---------------------------------------------------------------------------
struct AttnState {
  f32x4 po[8];
  float mrow[4];
  float lrow[4];
};

DEV void attn_tile(const unsigned short* K_, const unsigned short* V_,
                   unsigned short* P_, const bf16x8* qf, AttnState& st_,
                   int kv0, int q0, int qmaxw, int lane)
{
  if (kv0 > qmaxw) return;
  const int l15 = lane & 15, lg = lane >> 4;

  // ---- QK^T (swizzle-corrected K reads) ----
  f32x4 st[2];
  #pragma unroll
  for (int sub = 0; sub < 2; ++sub) {
    f32x4 s = {};
    const int kvloc = sub * 16 + l15;
    #pragma unroll
    for (int dt = 0; dt < 4; ++dt) {
      const int slot = (dt * 4 + lg) ^ (kvloc & 7);
      bf16x8 kf = *(const bf16x8*)&K_[kvloc * 128 + slot * 8];
      s = mfma16(qf[dt], kf, s);
    }
    st[sub] = s;
  }
  // ---- scale + causal mask ----
  #pragma unroll
  for (int sub = 0; sub < 2; ++sub)
    #pragma unroll
    for (int j = 0; j < 4; ++j) {
      const float val = st[sub][j] * 0.08838834764831845f;
      const int kv = kv0 + sub * 16 + l15;
      st[sub][j] = (kv > q0 + j) ? NEG_BIG : val;
    }
  // ---- online softmax (16-lane row reductions) ----
  float pm[4];
  #pragma unroll
  for (int j = 0; j < 4; ++j) pm[j] = fmaxf(st[0][j], st[1][j]);
  #pragma unroll
  for (int off = 1; off < 16; off <<= 1)
    #pragma unroll
    for (int j = 0; j < 4; ++j) pm[j] = fmaxf(pm[j], __shfl_xor(pm[j], off));
  float corr[4];
  #pragma unroll
  for (int j = 0; j < 4; ++j) {
    const float mn = fmaxf(st_.mrow[j], pm[j]);
    corr[j] = __expf(st_.mrow[j] - mn);
    st_.mrow[j] = mn;
  }
  float rs[4] = {0.f, 0.f, 0.f, 0.f};
  #pragma unroll
  for (int sub = 0; sub < 2; ++sub)
    #pragma unroll
    for (int j = 0; j < 4; ++j) {
      const float pv = __expf(st[sub][j] - st_.mrow[j]);
      st[sub][j] = pv;
      rs[j] += pv;
    }
  #pragma unroll
  for (int off = 1; off < 16; off <<= 1)
    #pragma unroll
    for (int j = 0; j < 4; ++j) rs[j] += __shfl_xor(rs[j], off);
  #pragma unroll
  for (int j = 0; j < 4; ++j) st_.lrow[j] = st_.lrow[j] * corr[j] + rs[j];
  #pragma unroll
  for (int dt = 0; dt < 8; ++dt)
    #pragma unroll
    for (int j = 0; j < 4; ++j) st_.po[dt][j] *= corr[j];

  // ---- P (D-layout) -> per-wave LDS -> A-operand layout ----
  #pragma unroll
  for (int sub = 0; sub < 2; ++sub)
    #pragma unroll
    for (int j = 0; j < 4; ++j)
      P_[(lg * 4 + j) * 40 + sub * 16 + l15] = f2bfu(st[sub][j]);
  asm volatile("s_waitcnt lgkmcnt(0)" ::: "memory");
  __builtin_amdgcn_sched_barrier(0);
  bf16x8 pf = *(const bf16x8*)&P_[l15 * 40 + lg * 8];

  // ---- PV: B-frag = contiguous b128 from swizzled V^T tile ----
  #pragma unroll
  for (int dt = 0; dt < 8; ++dt) {
    const int d = dt * 16 + l15;
    bf16x8 vf = *(const bf16x8*)&V_[d * 32 + ((lg ^ (l15 >> 2)) * 8)];
    st_.po[dt] = mfma16(pf, vf, st_.po[dt]);
  }
}

__global__ __launch_bounds__(256) void attn_fwd(
    const __hip_bfloat16* __restrict__ qk,
    const __hip_bfloat16* __restrict__ VT,
    __hip_bfloat16* __restrict__ O)
{
  __shared__ __align__(16) unsigned short ldsK[2][32 * 128];
  __shared__ __align__(16) unsigned short ldsV[2][128 * 32];
  __shared__ __align__(16) unsigned short ldsP[4][16 * 40];

  const int tid  = threadIdx.x;
  const int w    = tid >> 6;
  const int lane = tid & 63;
  const int qtA = blockIdx.x;        // 0..15
  const int qtB = 31 - qtA;          // 16..31
  const int h  = blockIdx.y;
  const int b  = blockIdx.z;
  const int hkv = h >> 2;

  const size_t LDQ = 2560;
  const __hip_bfloat16* Qb = qk + (size_t)b * 2048 * LDQ + h * 128;
  const __hip_bfloat16* Kb = qk + (size_t)b * 2048 * LDQ + 2048 + hkv * 128;
  const __hip_bfloat16* Vb = VT + (size_t)(hkv * 128) * 4096 + b * 2048;

  // K staging: dest row i*16 + krow, swizzled source column slot
  const int krow = tid >> 4;
  const int kcol = ((tid & 15) ^ (krow & 7)) * 8;
  // V staging: dest d-row i*64 + vdrow, swizzled source kv-slot
  const int vdrow = tid >> 2;
  const int vs8 = ((tid & 3) ^ ((tid >> 4) & 3)) * 8;

  const int l15 = lane & 15;
  const int koff = (lane >> 4) * 8;

  bf16x8 qfA[4], qfB[4];
  {
    const int qrA = qtA * 64 + w * 16 + l15;
    const int qrB = qtB * 64 + w * 16 + l15;
    #pragma unroll
    for (int dt = 0; dt < 4; ++dt) {
      qfA[dt] = *(const bf16x8*)(Qb + (size_t)qrA * LDQ + dt * 32 + koff);
      qfB[dt] = *(const bf16x8*)(Qb + (size_t)qrB * LDQ + dt * 32 + koff);
    }
  }

  const int ntA = 2 * qtA + 2;
  const int T   = 66;

#define STAGE(kv0_, buf_) do { \
    _Pragma("unroll") \
    for (int i = 0; i < 2; ++i) \
      gl_lds16(Kb + (size_t)((kv0_) + i * 16 + krow) * LDQ + kcol, \
               &ldsK[buf_][i * 2048 + w * 512]); \
    _Pragma("unroll") \
    for (int i = 0; i < 2; ++i) \
      gl_lds16(Vb + (size_t)(i * 64 + vdrow) * 4096 + (kv0_) + vs8, \
               &ldsV[buf_][i * 2048 + w * 512]); \
  } while (0)

  STAGE(0, 0);
  wait_vm0();
  __syncthreads();

  // ---------------- half A ----------------
  {
    AttnState st_;
    #pragma unroll
    for (int dt = 0; dt < 8; ++dt) st_.po[dt] = f32x4{};
    #pragma unroll
    for (int j = 0; j < 4; ++j) { st_.mrow[j] = NEG_BIG; st_.lrow[j] = 0.f; }
    const int q0 = qtA * 64 + w * 16 + (lane >> 4) * 4;
    const int qm = qtA * 64 + w * 16 + 15;
    for (int t = 0; t < ntA; ++t) {
      const int nx = t + 1;
      const int nkv0 = (nx < ntA ? nx : nx - ntA) * 32;
      STAGE(nkv0, nx & 1);
      attn_tile(ldsK[t & 1], ldsV[t & 1], ldsP[w], qfA, st_, t * 32, q0, qm, lane);
      wait_vm0();
      __syncthreads();
    }
    #pragma unroll
    for (int j = 0; j < 4; ++j) {
      const float inv = 1.0f / st_.lrow[j];
      const int q = q0 + j;
      #pragma unroll
      for (int dt = 0; dt < 8; ++dt)
        O[((size_t)b * 2048 + q) * 2048 + h * 128 + dt * 16 + l15] =
            __float2bfloat16(st_.po[dt][j] * inv);
    }
  }

  // ---------------- half B ----------------
  {
    AttnState st_;
    #pragma unroll
    for (int dt = 0; dt < 8; ++dt) st_.po[dt] = f32x4{};
    #pragma unroll
    for (int j = 0; j < 4; ++j) { st_.mrow[j] = NEG_BIG; st_.lrow[j] = 0.f; }
    const int q0 = qtB * 64 + w * 16 + (lane >> 4) * 4;
    const int qm = qtB * 64 + w * 16 + 15;
    for (int t = ntA; t < T; ++t) {
      const int nx = t + 1;
      if (nx < T) STAGE((nx - ntA) * 32, nx & 1);
      attn_tile(ldsK[t & 1], ldsV[t & 1], ldsP[w], qfB, st_, (t - ntA) * 32, q0, qm, lane);
      wait_vm0();
      __syncthreads();
    }
    #pragma unroll
    for (int j = 0; j < 4; ++j) {
      const float inv = 1.0f / st_.lrow[j];
      const int q = q0 + j;
      #pragma unroll
      for (int dt = 0; dt < 8; ++dt)
        O[((size_t)b * 2048 + q) * 2048 + h * 128 + dt * 16 + l15] =
            __float2bfloat16(st_.po[dt][j] * inv);
    }
  }
#undef STAGE
}

// ---------------------------------------------------------------------------
extern "C" void kernel_launch(void* const* d_in, const int* in_sizes, int n_in,
                              void* d_out, int out_size, void* d_ws, size_t ws_size,
                              hipStream_t stream) {
  (void)in_sizes; (void)n_in; (void)out_size; (void)ws_size;
  const float* x    = (const float*)d_in[0];
  const float* rope = (const float*)d_in[1];
  const float* wq   = (const float*)d_in[2];
  const float* wk   = (const float*)d_in[3];
  const float* wv   = (const float*)d_in[4];
  const float* wo   = (const float*)d_in[5];
  const float* qnw  = (const float*)d_in[6];
  const float* knw  = (const float*)d_in[7];
  float* out = (float*)d_out;

  // Workspace (bf16), 79.8 MB total:
  __hip_bfloat16* xb  = (__hip_bfloat16*)d_ws;            // [4096][2048]
  __hip_bfloat16* wb  = xb  + (size_t)4096 * 2048;        // [3072][2048] wq|wk|wv
  __hip_bfloat16* wob = wb  + (size_t)3072 * 2048;        // [2048][2048]
  __hip_bfloat16* qkb = wob + (size_t)2048 * 2048;        // [4096][2560] q|k
  __hip_bfloat16* vt  = qkb + (size_t)4096 * 2560;        // [512][4096]  V^T
  __hip_bfloat16* att = vt  + (size_t)512 * 4096;         // [4096][2048]

  cvt_f32_bf16<<<8192, 256, 0, stream>>>(x,  xb,  2097152);
  cvt_f32_bf16<<<4096, 256, 0, stream>>>(wq, wb,                     1048576);
  cvt_f32_bf16<<<1024, 256, 0, stream>>>(wk, wb + (size_t)2048*2048,  262144);
  cvt_f32_bf16<<<1024, 256, 0, stream>>>(wv, wb + (size_t)2560*2048,  262144);
  cvt_f32_bf16<<<4096, 256, 0, stream>>>(wo, wob,                    1048576);

  // QK projection -> qkb [4096][2560]
  gemm_bt<__hip_bfloat16, false><<<dim3(20, 32), 256, 0, stream>>>(
      xb, wb, qkb, 4096, 2560, 2048, 2560);
  // V projection, transposed epilogue -> vt [512][4096]
  gemm_bt<__hip_bfloat16, true><<<dim3(4, 32), 256, 0, stream>>>(
      xb, wb + (size_t)2560 * 2048, vt, 4096, 512, 2048, 4096);
  // per-head RMSNorm + RoPE on q,k (in place)
  rmsnorm_rope<<<20480, 256, 0, stream>>>(qkb, rope, qnw, knw);
  // causal GQA attention
  attn_fwd<<<dim3(16, 16, 2), 256, 0, stream>>>(qkb, vt, att);
  // output projection -> f32 out
  gemm_bt<float, false><<<dim3(16, 32), 256, 0, stream>>>(
      att, wob, out, 4096, 2048, 2048, 2048);
}

// Round 6
// 382.523 us; speedup vs baseline: 1.9690x; 1.1031x over previous
//
#include <hip/hip_runtime.h>
#include <hip/hip_bf16.h>
#include <stdint.h>

typedef float f32x4 __attribute__((ext_vector_type(4)));
typedef __bf16 bf16x8 __attribute__((ext_vector_type(8)));
typedef unsigned short u16x4 __attribute__((ext_vector_type(4)));

#define DEV __device__ __forceinline__
#define NEG_BIG (-3.0e38f)
// 1/sqrt(128) * log2(e): QK^T scores arrive pre-scaled for exp2
#define QSCALE_LOG2E 0.12751744532f

DEV f32x4 mfma16(bf16x8 a, bf16x8 b, f32x4 c) {
  return __builtin_amdgcn_mfma_f32_16x16x32_bf16(a, b, c, 0, 0, 0);
}

// global -> LDS direct copy, 16B per lane. LDS dest is wave-uniform base;
// HW writes base + lane*16. Global src is per-lane.
DEV void gl_lds16(const void* g, void* l) {
  __builtin_amdgcn_global_load_lds(
      (const __attribute__((address_space(1))) void*)g,
      (__attribute__((address_space(3))) void*)l,
      16, 0, 0);
}

DEV void wait_vm0() {
  asm volatile("s_waitcnt vmcnt(0)" ::: "memory");
  __builtin_amdgcn_sched_barrier(0);
}

DEV unsigned short f2bfu(float f) {
  __hip_bfloat16 h = __float2bfloat16(f);
  return __builtin_bit_cast(unsigned short, h);
}

// ---------------------------------------------------------------------------
// Fused f32 -> bf16 conversion for all 5 inputs (one launch).
// Regions (float4 units): x 2097152 | wq 1048576 | wk 262144 | wv 262144 | wo 1048576
// ---------------------------------------------------------------------------
__global__ __launch_bounds__(256) void cvt_all(
    const float* __restrict__ x,  const float* __restrict__ wq,
    const float* __restrict__ wk, const float* __restrict__ wv,
    const float* __restrict__ wo,
    __hip_bfloat16* __restrict__ xb, __hip_bfloat16* __restrict__ wb,
    __hip_bfloat16* __restrict__ wob)
{
  int i = blockIdx.x * 256 + threadIdx.x;
  const float* s; __hip_bfloat16* d;
  if (i < 2097152)      { s = x;  d = xb; }
  else if (i < 3145728) { s = wq; d = wb;                        i -= 2097152; }
  else if (i < 3407872) { s = wk; d = wb + (size_t)2048 * 2048;  i -= 3145728; }
  else if (i < 3670016) { s = wv; d = wb + (size_t)2560 * 2048;  i -= 3407872; }
  else                  { s = wo; d = wob;                       i -= 3670016; }
  const float4 v = ((const float4*)s)[i];
  u16x4 o;
  o[0] = f2bfu(v.x); o[1] = f2bfu(v.y); o[2] = f2bfu(v.z); o[3] = f2bfu(v.w);
  ((u16x4*)d)[i] = o;
}

// ---------------------------------------------------------------------------
// GEMM: C = A * B^T  (A: MxK bf16, B: NxK bf16). 128x128 tile, BK=32, dbuf.
// TRANS=true writes C transposed: C[n*ldc + m] (used to emit V^T directly).
// ---------------------------------------------------------------------------
DEV void storeC(__hip_bfloat16* C, size_t idx, float v) { C[idx] = __float2bfloat16(v); }
DEV void storeC(float* C, size_t idx, float v) { C[idx] = v; }

template <typename OutT, bool TRANS>
__global__ __launch_bounds__(256) void gemm_bt(
    const __hip_bfloat16* __restrict__ A,
    const __hip_bfloat16* __restrict__ B,
    OutT* __restrict__ C,
    int M, int N, int K, int ldc)
{
  __shared__ __align__(16) unsigned short ldsA[2][128 * 32];
  __shared__ __align__(16) unsigned short ldsB[2][128 * 32];

  const int tid  = threadIdx.x;
  const int w    = tid >> 6;
  const int lane = tid & 63;
  const int mbase = blockIdx.y * 128;
  const int nbase = blockIdx.x * 128;
  const int wr = (w >> 1) * 64;
  const int wc = (w & 1) * 64;

  const int srow = tid >> 2;
  const int scol = (tid & 3) * 8;
  const __hip_bfloat16* Ag = A + (size_t)(mbase + srow) * K + scol;
  const __hip_bfloat16* Bg = B + (size_t)(nbase + srow) * K + scol;

  f32x4 acc[4][4] = {};

  const int KT = K >> 5;
  int cur = 0;

  #pragma unroll
  for (int i = 0; i < 2; ++i) {
    gl_lds16(Ag + (size_t)i * 64 * K, &ldsA[0][i * 2048 + w * 512]);
    gl_lds16(Bg + (size_t)i * 64 * K, &ldsB[0][i * 2048 + w * 512]);
  }
  wait_vm0();
  __syncthreads();

  const int arow = wr + (lane & 15);
  const int brow = wc + (lane & 15);
  const int koff = (lane >> 4) * 8;

  for (int kt = 0; kt < KT; ++kt) {
    if (kt + 1 < KT) {
      const int k0 = (kt + 1) << 5;
      #pragma unroll
      for (int i = 0; i < 2; ++i) {
        gl_lds16(Ag + (size_t)i * 64 * K + k0, &ldsA[cur ^ 1][i * 2048 + w * 512]);
        gl_lds16(Bg + (size_t)i * 64 * K + k0, &ldsB[cur ^ 1][i * 2048 + w * 512]);
      }
    }
    bf16x8 af[4], bfr[4];
    #pragma unroll
    for (int mi = 0; mi < 4; ++mi)
      af[mi] = *(const bf16x8*)&ldsA[cur][(arow + mi * 16) * 32 + koff];
    #pragma unroll
    for (int ni = 0; ni < 4; ++ni)
      bfr[ni] = *(const bf16x8*)&ldsB[cur][(brow + ni * 16) * 32 + koff];
    #pragma unroll
    for (int mi = 0; mi < 4; ++mi)
      #pragma unroll
      for (int ni = 0; ni < 4; ++ni)
        acc[mi][ni] = mfma16(af[mi], bfr[ni], acc[mi][ni]);
    wait_vm0();
    __syncthreads();
    cur ^= 1;
  }

  #pragma unroll
  for (int mi = 0; mi < 4; ++mi)
    #pragma unroll
    for (int ni = 0; ni < 4; ++ni)
      #pragma unroll
      for (int j = 0; j < 4; ++j) {
        const int m = mbase + wr + mi * 16 + (lane >> 4) * 4 + j;
        const int n = nbase + wc + ni * 16 + (lane & 15);
        if (TRANS) storeC(C, (size_t)n * ldc + m, acc[mi][ni][j]);
        else       storeC(C, (size_t)m * ldc + n, acc[mi][ni][j]);
      }
}

// ---------------------------------------------------------------------------
// Per-head RMSNorm + RoPE, in-place on the bf16 qk buffer (stride 2560).
// Q heads are additionally scaled by 1/sqrt(HD) * log2(e)  (softmax via exp2).
// ---------------------------------------------------------------------------
__global__ __launch_bounds__(256) void rmsnorm_rope(
    __hip_bfloat16* __restrict__ qk,
    const float* __restrict__ rope,
    const float* __restrict__ qw,
    const float* __restrict__ kw)
{
  const int v = blockIdx.x * 4 + (threadIdx.x >> 6);
  const int lane = threadIdx.x & 63;
  const int row = v / 20;
  const int hh  = v % 20;
  const int s   = row & 2047;

  __hip_bfloat16* p = qk + (size_t)row * 2560 +
                      (hh < 16 ? hh * 128 : 2048 + (hh - 16) * 128);
  const float* wn = (hh < 16) ? qw : kw;
  const float os = (hh < 16) ? QSCALE_LOG2E : 1.0f;

  float x0 = __bfloat162float(p[lane]);
  float x1 = __bfloat162float(p[lane + 64]);
  float ss = x0 * x0 + x1 * x1;
  #pragma unroll
  for (int off = 1; off < 64; off <<= 1) ss += __shfl_xor(ss, off);
  const float rn = rsqrtf(ss * (1.0f / 128.0f) + 1e-6f);
  x0 *= rn * wn[lane];
  x1 *= rn * wn[lane + 64];

  const float* rc = rope + (size_t)s * 256;
  p[lane]      = __float2bfloat16((x0 * rc[lane]      - x1 * rc[128 + lane]) * os);
  p[lane + 64] = __float2bfloat16((x1 * rc[64 + lane] + x0 * rc[192 + lane]) * os);
}

// ---------------------------------------------------------------------------
// Causal GQA flash attention, KVBLK=64.
//  - block (qtA, h, b) handles q-tiles qtA and 31-qtA: uniform 33 KV tiles
//  - K: [64 kv][128 d] LDS, both-sides XOR swizzle (slot ^= kv&7)
//  - V: from global V^T [512][4096]; LDS [128 d][64 kv], slot ^= d&7
//  - P: per-wave [16][72]; mask only on diagonal tile; defer-max (THR=8)
//  - softmax in exp2 units (Q pre-scaled by scale*log2e)
// ---------------------------------------------------------------------------
struct AttnState {
  f32x4 po[8];
  float mrow[4];
  float lrow[4];
};

DEV void attn_tile(const unsigned short* K_, const unsigned short* V_,
                   unsigned short* P_, const bf16x8* qf, AttnState& st_,
                   int kv0, int q0, int qminw, int lane)
{
  const int l15 = lane & 15, lg = lane >> 4;

  // ---- QK^T: 4 kv-subtiles of 16 (swizzle-corrected K reads) ----
  f32x4 st[4];
  #pragma unroll
  for (int sub = 0; sub < 4; ++sub) {
    f32x4 s = {};
    const int kvloc = sub * 16 + l15;
    #pragma unroll
    for (int dt = 0; dt < 4; ++dt) {
      const int slot = (dt * 4 + lg) ^ (kvloc & 7);
      bf16x8 kf = *(const bf16x8*)&K_[kvloc * 128 + slot * 8];
      s = mfma16(qf[dt], kf, s);
    }
    st[sub] = s;
  }
  // ---- causal mask: only the diagonal tile needs it ----
  if (kv0 + 63 > qminw) {
    #pragma unroll
    for (int sub = 0; sub < 4; ++sub)
      #pragma unroll
      for (int j = 0; j < 4; ++j) {
        const int kv = kv0 + sub * 16 + l15;
        if (kv > q0 + j) st[sub][j] = NEG_BIG;
      }
  }
  // ---- tile max (16-lane row reduction) ----
  float pm[4];
  #pragma unroll
  for (int j = 0; j < 4; ++j)
    pm[j] = fmaxf(fmaxf(st[0][j], st[1][j]), fmaxf(st[2][j], st[3][j]));
  #pragma unroll
  for (int off = 1; off < 16; off <<= 1)
    #pragma unroll
    for (int j = 0; j < 4; ++j) pm[j] = fmaxf(pm[j], __shfl_xor(pm[j], off));
  // ---- defer-max: rescale only when max grew by > 8 (log2 units) ----
  bool need = false;
  #pragma unroll
  for (int j = 0; j < 4; ++j) need = need || (pm[j] > st_.mrow[j] + 8.f);
  if (__any(need)) {
    #pragma unroll
    for (int j = 0; j < 4; ++j) {
      const float mn = fmaxf(st_.mrow[j], pm[j]);
      const float corr = exp2f(st_.mrow[j] - mn);
      st_.mrow[j] = mn;
      st_.lrow[j] *= corr;
      #pragma unroll
      for (int dt = 0; dt < 8; ++dt) st_.po[dt][j] *= corr;
    }
  }
  // ---- P = exp2(st - m), row-sum ----
  float rs[4] = {0.f, 0.f, 0.f, 0.f};
  #pragma unroll
  for (int sub = 0; sub < 4; ++sub)
    #pragma unroll
    for (int j = 0; j < 4; ++j) {
      const float pv = exp2f(st[sub][j] - st_.mrow[j]);
      st[sub][j] = pv;
      rs[j] += pv;
    }
  #pragma unroll
  for (int off = 1; off < 16; off <<= 1)
    #pragma unroll
    for (int j = 0; j < 4; ++j) rs[j] += __shfl_xor(rs[j], off);
  #pragma unroll
  for (int j = 0; j < 4; ++j) st_.lrow[j] += rs[j];

  // ---- P (D-layout) -> per-wave LDS -> A-operand layout ----
  #pragma unroll
  for (int sub = 0; sub < 4; ++sub)
    #pragma unroll
    for (int j = 0; j < 4; ++j)
      P_[(lg * 4 + j) * 72 + sub * 16 + l15] = f2bfu(st[sub][j]);
  asm volatile("s_waitcnt lgkmcnt(0)" ::: "memory");
  __builtin_amdgcn_sched_barrier(0);
  bf16x8 pf0 = *(const bf16x8*)&P_[l15 * 72 + lg * 8];
  bf16x8 pf1 = *(const bf16x8*)&P_[l15 * 72 + 32 + lg * 8];

  // ---- PV: two K=32 MFMAs per 16-d block, swizzled V^T reads ----
  #pragma unroll
  for (int dt = 0; dt < 8; ++dt) {
    const int d = dt * 16 + l15;
    bf16x8 v0 = *(const bf16x8*)&V_[d * 64 + ((lg       ^ (d & 7))) * 8];
    bf16x8 v1 = *(const bf16x8*)&V_[d * 64 + (((4 + lg) ^ (d & 7))) * 8];
    st_.po[dt] = mfma16(pf0, v0, st_.po[dt]);
    st_.po[dt] = mfma16(pf1, v1, st_.po[dt]);
  }
}

__global__ __launch_bounds__(256) void attn_fwd(
    const __hip_bfloat16* __restrict__ qk,
    const __hip_bfloat16* __restrict__ VT,
    __hip_bfloat16* __restrict__ O)
{
  __shared__ __align__(16) unsigned short ldsK[2][64 * 128];
  __shared__ __align__(16) unsigned short ldsV[2][128 * 64];
  __shared__ __align__(16) unsigned short ldsP[4][16 * 72];

  const int tid  = threadIdx.x;
  const int w    = tid >> 6;
  const int lane = tid & 63;
  const int qtA = blockIdx.x;        // 0..15
  const int qtB = 31 - qtA;          // 16..31
  const int h  = blockIdx.y;
  const int b  = blockIdx.z;
  const int hkv = h >> 2;

  const size_t LDQ = 2560;
  const __hip_bfloat16* Qb = qk + (size_t)b * 2048 * LDQ + h * 128;
  const __hip_bfloat16* Kb = qk + (size_t)b * 2048 * LDQ + 2048 + hkv * 128;
  const __hip_bfloat16* Vb = VT + (size_t)(hkv * 128) * 4096 + b * 2048;

  // K staging: dest row i*16 + krow, swizzled source column slot
  const int krow = tid >> 4;
  const int kcol = ((tid & 15) ^ (krow & 7)) * 8;
  // V staging: dest d-row i*32 + vdrow (64 kv elems), swizzled source kv slot
  const int vdrow = tid >> 3;
  const int vs8 = ((tid & 7) ^ (vdrow & 7)) * 8;

  const int l15 = lane & 15;
  const int koff = (lane >> 4) * 8;

  bf16x8 qfA[4], qfB[4];
  {
    const int qrA = qtA * 64 + w * 16 + l15;
    const int qrB = qtB * 64 + w * 16 + l15;
    #pragma unroll
    for (int dt = 0; dt < 4; ++dt) {
      qfA[dt] = *(const bf16x8*)(Qb + (size_t)qrA * LDQ + dt * 32 + koff);
      qfB[dt] = *(const bf16x8*)(Qb + (size_t)qrB * LDQ + dt * 32 + koff);
    }
  }

  const int ntA = qtA + 1;           // 64-wide KV tiles for half A
  const int T   = 33;                // ntA + ntB

#define STAGE(kv0_, buf_) do { \
    _Pragma("unroll") \
    for (int i = 0; i < 4; ++i) \
      gl_lds16(Kb + (size_t)((kv0_) + i * 16 + krow) * LDQ + kcol, \
               &ldsK[buf_][i * 2048 + w * 512]); \
    _Pragma("unroll") \
    for (int i = 0; i < 4; ++i) \
      gl_lds16(Vb + (size_t)(i * 32 + vdrow) * 4096 + (kv0_) + vs8, \
               &ldsV[buf_][i * 2048 + w * 512]); \
  } while (0)

  STAGE(0, 0);
  wait_vm0();
  __syncthreads();

  // ---------------- half A ----------------
  {
    AttnState st_;
    #pragma unroll
    for (int dt = 0; dt < 8; ++dt) st_.po[dt] = f32x4{};
    #pragma unroll
    for (int j = 0; j < 4; ++j) { st_.mrow[j] = NEG_BIG; st_.lrow[j] = 0.f; }
    const int q0 = qtA * 64 + w * 16 + (lane >> 4) * 4;
    const int qminw = qtA * 64 + w * 16;
    for (int t = 0; t < ntA; ++t) {
      const int nx = t + 1;
      const int nkv0 = (nx < ntA ? nx : nx - ntA) * 64;
      STAGE(nkv0, nx & 1);
      attn_tile(ldsK[t & 1], ldsV[t & 1], ldsP[w], qfA, st_, t * 64, q0, qminw, lane);
      wait_vm0();
      __syncthreads();
    }
    #pragma unroll
    for (int j = 0; j < 4; ++j) {
      const float inv = 1.0f / st_.lrow[j];
      const int q = q0 + j;
      #pragma unroll
      for (int dt = 0; dt < 8; ++dt)
        O[((size_t)b * 2048 + q) * 2048 + h * 128 + dt * 16 + l15] =
            __float2bfloat16(st_.po[dt][j] * inv);
    }
  }

  // ---------------- half B ----------------
  {
    AttnState st_;
    #pragma unroll
    for (int dt = 0; dt < 8; ++dt) st_.po[dt] = f32x4{};
    #pragma unroll
    for (int j = 0; j < 4; ++j) { st_.mrow[j] = NEG_BIG; st_.lrow[j] = 0.f; }
    const int q0 = qtB * 64 + w * 16 + (lane >> 4) * 4;
    const int qminw = qtB * 64 + w * 16;
    for (int t = ntA; t < T; ++t) {
      const int nx = t + 1;
      if (nx < T) STAGE((nx - ntA) * 64, nx & 1);
      attn_tile(ldsK[t & 1], ldsV[t & 1], ldsP[w], qfB, st_, (t - ntA) * 64, q0, qminw, lane);
      wait_vm0();
      __syncthreads();
    }
    #pragma unroll
    for (int j = 0; j < 4; ++j) {
      const float inv = 1.0f / st_.lrow[j];
      const int q = q0 + j;
      #pragma unroll
      for (int dt = 0; dt < 8; ++dt)
        O[((size_t)b * 2048 + q) * 2048 + h * 128 + dt * 16 + l15] =
            __float2bfloat16(st_.po[dt][j] * inv);
    }
  }
#undef STAGE
}

// ---------------------------------------------------------------------------
extern "C" void kernel_launch(void* const* d_in, const int* in_sizes, int n_in,
                              void* d_out, int out_size, void* d_ws, size_t ws_size,
                              hipStream_t stream) {
  (void)in_sizes; (void)n_in; (void)out_size; (void)ws_size;
  const float* x    = (const float*)d_in[0];
  const float* rope = (const float*)d_in[1];
  const float* wq   = (const float*)d_in[2];
  const float* wk   = (const float*)d_in[3];
  const float* wv   = (const float*)d_in[4];
  const float* wo   = (const float*)d_in[5];
  const float* qnw  = (const float*)d_in[6];
  const float* knw  = (const float*)d_in[7];
  float* out = (float*)d_out;

  // Workspace (bf16), 79.8 MB total:
  __hip_bfloat16* xb  = (__hip_bfloat16*)d_ws;            // [4096][2048]
  __hip_bfloat16* wb  = xb  + (size_t)4096 * 2048;        // [3072][2048] wq|wk|wv
  __hip_bfloat16* wob = wb  + (size_t)3072 * 2048;        // [2048][2048]
  __hip_bfloat16* qkb = wob + (size_t)2048 * 2048;        // [4096][2560] q|k
  __hip_bfloat16* vt  = qkb + (size_t)4096 * 2560;        // [512][4096]  V^T
  __hip_bfloat16* att = vt  + (size_t)512 * 4096;         // [4096][2048]

  // fused f32->bf16 conversion (one launch)
  cvt_all<<<18432, 256, 0, stream>>>(x, wq, wk, wv, wo, xb, wb, wob);

  // QK projection -> qkb [4096][2560]
  gemm_bt<__hip_bfloat16, false><<<dim3(20, 32), 256, 0, stream>>>(
      xb, wb, qkb, 4096, 2560, 2048, 2560);
  // V projection, transposed epilogue -> vt [512][4096]
  gemm_bt<__hip_bfloat16, true><<<dim3(4, 32), 256, 0, stream>>>(
      xb, wb + (size_t)2560 * 2048, vt, 4096, 512, 2048, 4096);
  // per-head RMSNorm + RoPE on q,k (in place; Q pre-scaled by scale*log2e)
  rmsnorm_rope<<<20480, 256, 0, stream>>>(qkb, rope, qnw, knw);
  // causal GQA attention
  attn_fwd<<<dim3(16, 16, 2), 256, 0, stream>>>(qkb, vt, att);
  // output projection -> f32 out
  gemm_bt<float, false><<<dim3(16, 32), 256, 0, stream>>>(
      att, wob, out, 4096, 2048, 2048, 2048);
}